// Round 8
// baseline (149.681 us; speedup 1.0000x reference)
//
#include <hip/hip_runtime.h>
#include <hip/hip_bf16.h>

// 3D bilateral filter, radius 2 (125 taps), input (2,1,128,128,128) f32.
// v8: cvt-free Schraudolph. Evidence trail: v5/v7 VALU-busy fits plain
// VALU=2cyc, pk_f32=4cyc, v_cvt_u32_f32~16cyc (quarter-rate conversion pipe)
// -> the 2 cvts per packed pair were ~32 of ~40 cyc. Replacement:
//   y = (2^23 + 15360 - 1024*log2-exponent) - t^2   (one pk_fma, f32)
//   y in [2^23,2^24) => low 16 bits of bits(y) == f16 encoding of 2^e
//   clamp y=max(y,2^23) => w=+0 for far/OOB taps (sentinel->-inf->clamp)
//   v_perm_b32 packs two taps' low16 -> f16x2 weight register
//   v_pk_add_f16 / v_pk_fma_f16 accumulate den/num (full rate)
// Tap values for num come from a second f16 LDS copy (clamped at staging so
// the sentinel stays finite: 0*finite=0, no NaN). Scale sR folded into both
// staged tiles; undone once in the epilogue (out = num/(den*sR)).
// Per 2 taps: 18 cyc vs v7's ~40. Keep v5/v7 shell: 16x8x8 tile, 4 vox/thread.

#define RADIUS 2
#define N 128
#define TX 16
#define TY 8
#define TZ 8
#define PITCH (TX + 2 * RADIUS)      // 20 floats per row
#define LYD (TY + 2 * RADIUS)        // 12
#define LZD (TZ + 2 * RADIUS)        // 12
#define LDS_SIZE (PITCH * LYD * LZD) // 2880 elements

#define LOG2E 1.4426950408889634f
#define BIG 1.0e18f
#define MAGIC 8388608.0f             // 2^23
#define BASE16 8403968.0f            // 2^23 + 15*1024  (f16 bias<<10)

typedef float f32x2 __attribute__((ext_vector_type(2)));
typedef _Float16 h16x2 __attribute__((ext_vector_type(2)));

static __device__ __forceinline__ float lo_f(unsigned u) {
  h16x2 t = __builtin_bit_cast(h16x2, u);
  return (float)t.x;
}
static __device__ __forceinline__ float hi_f(unsigned u) {
  h16x2 t = __builtin_bit_cast(h16x2, u);
  return (float)t.y;
}

__global__ __launch_bounds__(256, 4) void bilateral3d_kernel(
    const float* __restrict__ in, const float* __restrict__ p_sx,
    const float* __restrict__ p_sy, const float* __restrict__ p_sz,
    const float* __restrict__ p_cs, float* __restrict__ out) {
  __shared__ float s[LDS_SIZE];       // scaled f32 tile
  __shared__ _Float16 h[LDS_SIZE];    // scaled f16 tile (clamped)

  const int tid = threadIdx.x;
  const int x0 = blockIdx.x * TX;
  const int y0 = blockIdx.y * TY;
  const int zb = blockIdx.z;  // low 4 bits = z-tile, bit 4 = batch
  const int z0 = (zb & 15) * TZ;
  const int b = zb >> 4;

  const float sxv = p_sx[0], syv = p_sy[0], szv = p_sz[0], csv = p_cs[0];
  const float K10 = 1024.0f * LOG2E;           // log2 scale -> f16-exponent units
  const float AX2 = K10 / (2.0f * sxv * sxv);
  const float AY2 = K10 / (2.0f * syv * syv);
  const float AZ2 = K10 / (2.0f * szv * szv);
  const float AX2_4 = 4.0f * AX2;
  const float sR = __builtin_sqrtf(K10 / (2.0f * csv * csv));  // range scale

  const float* vol = in + (size_t)b * (N * N * N);

  // --- stage scaled f32 + clamped f16 tiles (OOB -> sentinel) ---
  for (int i = tid; i < LDS_SIZE; i += 256) {
    int lx = i % PITCH;
    int t = i / PITCH;
    int ly = t % LYD;
    int lz = t / LYD;
    int gx = x0 + lx - RADIUS;
    int gy = y0 + ly - RADIUS;
    int gz = z0 + lz - RADIUS;
    float v = BIG;
    if ((unsigned)gx < N && (unsigned)gy < N && (unsigned)gz < N)
      v = vol[((size_t)gz * N + gy) * N + gx];
    float vs = v * sR;
    s[i] = vs;
    h[i] = (_Float16)__builtin_fminf(vs, 60000.0f);  // keep sentinel finite in f16
  }
  __syncthreads();

  const int tx = tid & 3;         // x-group: voxels x0+4tx .. x0+4tx+3
  const int ty = (tid >> 2) & 7;
  const int tz = tid >> 5;

  const int xw = 4 * tx;

  // centers (scaled): words [xw+2 .. xw+5] of the (dz=0,dy=0) row
  const int cbase = ((tz + RADIUS) * LYD + (ty + RADIUS)) * PITCH + xw;
  const float xs0 = s[cbase + 2];
  const float xs1 = s[cbase + 3];
  const float xs2 = s[cbase + 4];
  const float xs3 = s[cbase + 5];
  f32x2 XS0, XS1, XS2, XS3;
  XS0.x = xs0; XS0.y = xs0;
  XS1.x = xs1; XS1.y = xs1;
  XS2.x = xs2; XS2.y = xs2;
  XS3.x = xs3; XS3.y = xs3;

  const unsigned* hw = (const unsigned*)h;  // f16-pair words

  // f16x2 accumulators (bit patterns); PK: lanes = two dx of one voxel;
  // SC: lanes = (voxel even, voxel odd)
  unsigned NUa0 = 0, NUa1 = 0, NUa2 = 0, NUa3 = 0;
  unsigned DEa0 = 0, DEa1 = 0, DEa2 = 0, DEa3 = 0;
  unsigned NUs01 = 0, NUs23 = 0, DEs01 = 0, DEs23 = 0;

  // packed tap pair: t = XS - Gs; y = CC2 - t^2; clamp; low16 pair -> f16x2 w
#define PK(XS2V, GS, H16, CC2, NUM, DEN)                                   \
  {                                                                        \
    f32x2 _t, _y;                                                          \
    asm("v_pk_add_f32 %0, %1, %2 neg_lo:[0,1] neg_hi:[0,1]"                \
        : "=v"(_t) : "v"(XS2V), "v"(GS));                                  \
    asm("v_pk_fma_f32 %0, %1, %1, %2 neg_lo:[0,1,0] neg_hi:[0,1,0]"        \
        : "=v"(_y) : "v"(_t), "v"(CC2));                                   \
    float _ax = __builtin_fmaxf(_y.x, MAGIC);                              \
    float _ay = __builtin_fmaxf(_y.y, MAGIC);                              \
    unsigned _w = __builtin_amdgcn_perm(__float_as_uint(_ay),              \
                                        __float_as_uint(_ax), 0x05040100); \
    asm("v_pk_add_f16 %0, %0, %1" : "+v"(DEN) : "v"(_w));                  \
    asm("v_pk_fma_f16 %0, %1, %2, %0" : "+v"(NUM) : "v"(_w), "v"(H16));    \
  }

  // leftover |dx|=2 taps, paired across two voxels (lanes = vA, vB)
#define SC2(XA, XB, GA, GB, H16, CC, NUM, DEN)                             \
  {                                                                        \
    float _ta = (XA) - (GA);                                               \
    float _tb = (XB) - (GB);                                               \
    float _ya = __builtin_fmaxf(fmaf(_ta, -_ta, (CC)), MAGIC);             \
    float _yb = __builtin_fmaxf(fmaf(_tb, -_tb, (CC)), MAGIC);             \
    unsigned _w = __builtin_amdgcn_perm(__float_as_uint(_yb),              \
                                        __float_as_uint(_ya), 0x05040100); \
    asm("v_pk_add_f16 %0, %0, %1" : "+v"(DEN) : "v"(_w));                  \
    asm("v_pk_fma_f16 %0, %1, %2, %0" : "+v"(NUM) : "v"(_w), "v"(H16));    \
  }

#pragma unroll 1
  for (int dz = -RADIUS; dz <= RADIUS; ++dz) {
    const float pz2 = AZ2 * (float)(dz * dz);
    const int zrow = (tz + RADIUS + dz) * LYD;
#pragma unroll
    for (int dy = -RADIUS; dy <= RADIUS; ++dy) {
      const float cc0 = BASE16 - (pz2 + AY2 * (float)(dy * dy));
      const float cm1 = cc0 - AX2;
      const float cm4 = cc0 - AX2_4;
      f32x2 P41, P01, P10, P14;
      P41.x = cm4; P41.y = cm1;  // dx (-2,-1)
      P01.x = cc0; P01.y = cm1;  // dx ( 0,+1)
      P10.x = cm1; P10.y = cc0;  // dx (-1, 0)
      P14.x = cm1; P14.y = cm4;  // dx (+1,+2)

      const int rb = (zrow + (ty + RADIUS + dy)) * PITCH + xw;
      const f32x2 G0 = *(const f32x2*)&s[rb];
      const f32x2 G1 = *(const f32x2*)&s[rb + 2];
      const f32x2 G2 = *(const f32x2*)&s[rb + 4];
      const f32x2 G3 = *(const f32x2*)&s[rb + 6];
      const int hb = rb >> 1;
      const unsigned H0 = hw[hb];      // {f0,f1} as f16
      const unsigned H1 = hw[hb + 1];  // {f2,f3}
      const unsigned H2 = hw[hb + 2];  // {f4,f5}
      const unsigned H3 = hw[hb + 3];  // {f6,f7}

      // voxel 0 (center f2): H0 -> dx(-2,-1), H1 -> dx(0,+1)
      PK(XS0, G0, H0, P41, NUa0, DEa0)
      PK(XS0, G1, H1, P01, NUa0, DEa0)
      // voxel 1 (center f3): H1 -> dx(-1,0), H2 -> dx(+1,+2)
      PK(XS1, G1, H1, P10, NUa1, DEa1)
      PK(XS1, G2, H2, P14, NUa1, DEa1)
      // voxel 2 (center f4): H1 -> dx(-2,-1), H2 -> dx(0,+1)
      PK(XS2, G1, H1, P41, NUa2, DEa2)
      PK(XS2, G2, H2, P01, NUa2, DEa2)
      // voxel 3 (center f5): H2 -> dx(-1,0), H3 -> dx(+1,+2)
      PK(XS3, G2, H2, P10, NUa3, DEa3)
      PK(XS3, G3, H3, P14, NUa3, DEa3)

      // leftovers: v0 taps f4 (H2.lo), v1 taps f1 (H0.hi)
      {
        unsigned Ga16 = __builtin_amdgcn_perm(H0, H2, 0x07060100);
        SC2(xs0, xs1, G2.x, G0.y, Ga16, cm4, NUs01, DEs01)
      }
      // v2 taps f6 (H3.lo), v3 taps f3 (H1.hi)
      {
        unsigned Gb16 = __builtin_amdgcn_perm(H1, H3, 0x07060100);
        SC2(xs2, xs3, G3.x, G1.y, Gb16, cm4, NUs23, DEs23)
      }
    }
  }

  const float num0 = lo_f(NUa0) + hi_f(NUa0) + lo_f(NUs01);
  const float num1 = lo_f(NUa1) + hi_f(NUa1) + hi_f(NUs01);
  const float num2 = lo_f(NUa2) + hi_f(NUa2) + lo_f(NUs23);
  const float num3 = lo_f(NUa3) + hi_f(NUa3) + hi_f(NUs23);
  const float den0 = lo_f(DEa0) + hi_f(DEa0) + lo_f(DEs01);
  const float den1 = lo_f(DEa1) + hi_f(DEa1) + hi_f(DEs01);
  const float den2 = lo_f(DEa2) + hi_f(DEa2) + lo_f(DEs23);
  const float den3 = lo_f(DEa3) + hi_f(DEa3) + hi_f(DEs23);

  float4 r;
  r.x = num0 / (den0 * sR);
  r.y = num1 / (den1 * sR);
  r.z = num2 / (den2 * sR);
  r.w = num3 / (den3 * sR);

  const int gz = z0 + tz, gy = y0 + ty;
  *(float4*)&out[(((size_t)b * N + gz) * N + gy) * N + (x0 + xw)] = r;
}

extern "C" void kernel_launch(void* const* d_in, const int* in_sizes, int n_in,
                              void* d_out, int out_size, void* d_ws, size_t ws_size,
                              hipStream_t stream) {
  const float* in = (const float*)d_in[0];
  const float* sx = (const float*)d_in[1];
  const float* sy = (const float*)d_in[2];
  const float* sz = (const float*)d_in[3];
  const float* cs = (const float*)d_in[4];
  float* out = (float*)d_out;

  dim3 grid(N / TX, N / TY, (N / TZ) * 2);  // 8 x 16 x 32
  bilateral3d_kernel<<<grid, 256, 0, stream>>>(in, sx, sy, sz, cs, out);
}